// Round 1
// baseline (1255.513 us; speedup 1.0000x reference)
//
#include <hip/hip_runtime.h>

#define N_NODES 100000
#define N_EDGES 1600000
#define N_GRAPHS 512
#define F 128
#define N_CONVS 4
#define SCAN_NBLK ((N_NODES + 1023) / 1024)   // 98

// ---------------- CSR build ----------------

__global__ void count_kernel(const int* __restrict__ dst, int* __restrict__ cnt) {
    int e = blockIdx.x * blockDim.x + threadIdx.x;
    if (e < N_EDGES) atomicAdd(&cnt[dst[e]], 1);
}

__global__ void dinv_kernel(const int* __restrict__ cnt, float* __restrict__ dinv) {
    int n = blockIdx.x * blockDim.x + threadIdx.x;
    if (n < N_NODES) dinv[n] = rsqrtf((float)cnt[n] + 2.0f);  // improved=True: +2 self loop
}

// Exclusive scan of cnt[] into rowptr[], hierarchical (1024 elems/block).
__global__ void scan1_kernel(const int* __restrict__ cnt, int* __restrict__ excl,
                             int* __restrict__ blksum) {
    __shared__ int sums[256];
    int t = threadIdx.x;
    int base = blockIdx.x * 1024 + t * 4;
    int v0 = 0, v1 = 0, v2 = 0, v3 = 0;
    if (base + 0 < N_NODES) v0 = cnt[base + 0];
    if (base + 1 < N_NODES) v1 = cnt[base + 1];
    if (base + 2 < N_NODES) v2 = cnt[base + 2];
    if (base + 3 < N_NODES) v3 = cnt[base + 3];
    int s = v0 + v1 + v2 + v3;
    sums[t] = s;
    __syncthreads();
    for (int off = 1; off < 256; off <<= 1) {
        int y = (t >= off) ? sums[t - off] : 0;
        __syncthreads();
        sums[t] += y;
        __syncthreads();
    }
    int pre = sums[t] - s;  // exclusive prefix of this thread's 4 elems
    if (base + 0 < N_NODES) excl[base + 0] = pre;
    if (base + 1 < N_NODES) excl[base + 1] = pre + v0;
    if (base + 2 < N_NODES) excl[base + 2] = pre + v0 + v1;
    if (base + 3 < N_NODES) excl[base + 3] = pre + v0 + v1 + v2;
    if (t == 255) blksum[blockIdx.x] = sums[255];
}

__global__ void scan2_kernel(int* __restrict__ blksum, int nblk) {
    __shared__ int sh[128];
    int t = threadIdx.x;
    int v = (t < nblk) ? blksum[t] : 0;
    sh[t] = v;
    __syncthreads();
    for (int off = 1; off < 128; off <<= 1) {
        int y = (t >= off) ? sh[t - off] : 0;
        __syncthreads();
        sh[t] += y;
        __syncthreads();
    }
    if (t < nblk) blksum[t] = sh[t] - v;  // exclusive block offsets
}

__global__ void scan3_kernel(int* __restrict__ rowptr, const int* __restrict__ blksum,
                             int* __restrict__ fill) {
    int t = threadIdx.x;
    int base = blockIdx.x * 1024 + t * 4;
    int off = blksum[blockIdx.x];
#pragma unroll
    for (int i = 0; i < 4; i++) {
        int idx = base + i;
        if (idx < N_NODES) {
            int v = rowptr[idx] + off;
            rowptr[idx] = v;
            fill[idx] = v;  // fill cursor starts at row begin
        }
    }
    if (blockIdx.x == 0 && t == 0) rowptr[N_NODES] = N_EDGES;
}

__global__ void fill_kernel(const int* __restrict__ src, const int* __restrict__ dst,
                            int* __restrict__ fill, int* __restrict__ col) {
    int e = blockIdx.x * blockDim.x + threadIdx.x;
    if (e < N_EDGES) {
        int pos = atomicAdd(&fill[dst[e]], 1);
        col[pos] = src[e];
    }
}

// ---------------- GEMM: H = X @ W   (M=100000, K=N=128, fp32) ----------------
// Block = 256 threads, 64 rows/block. X tile staged in LDS (padded stride 132),
// W read from global (64 KB, L1/L2-resident across all blocks).

__global__ __launch_bounds__(256) void gemm_kernel(const float* __restrict__ X,
                                                   const float* __restrict__ W,
                                                   float* __restrict__ H) {
    __shared__ float xs[64 * 132];
    int t = threadIdx.x;
    int row0 = blockIdx.x * 64;

    // stage 64x128 fp32 tile, float4 loads
#pragma unroll
    for (int i = 0; i < 8; i++) {
        int idx = i * 256 + t;      // 0..2047
        int r = idx >> 5;           // 0..63
        int c4 = idx & 31;          // float4 index within row
        float4 v = make_float4(0.f, 0.f, 0.f, 0.f);
        int row = row0 + r;
        if (row < N_NODES) v = *(const float4*)(X + (size_t)row * F + c4 * 4);
        *(float4*)(&xs[r * 132 + c4 * 4]) = v;
    }
    __syncthreads();

    int cg = t & 31;   // col group: cols cg*4 .. cg*4+3
    int rg = t >> 5;   // row group: rows rg*8 .. rg*8+7
    const float4* W4 = (const float4*)W;

    float acc[8][4];
#pragma unroll
    for (int i = 0; i < 8; i++)
#pragma unroll
        for (int j = 0; j < 4; j++) acc[i][j] = 0.f;

#pragma unroll 4
    for (int k = 0; k < F; k++) {
        float4 w = W4[k * 32 + cg];
#pragma unroll
        for (int i = 0; i < 8; i++) {
            float xv = xs[(rg * 8 + i) * 132 + k];
            acc[i][0] = fmaf(xv, w.x, acc[i][0]);
            acc[i][1] = fmaf(xv, w.y, acc[i][1]);
            acc[i][2] = fmaf(xv, w.z, acc[i][2]);
            acc[i][3] = fmaf(xv, w.w, acc[i][3]);
        }
    }

#pragma unroll
    for (int i = 0; i < 8; i++) {
        int row = row0 + rg * 8 + i;
        if (row < N_NODES) {
            float4 o = make_float4(acc[i][0], acc[i][1], acc[i][2], acc[i][3]);
            *(float4*)(H + (size_t)row * F + cg * 4) = o;
        }
    }
}

// ---------------- Aggregation: x_out = relu(agg + 2*dinv^2*h + b) ----------------
// One block per node, thread = feature channel. CSR gather: coalesced 512 B rows.

__global__ __launch_bounds__(128) void agg_kernel(const float* __restrict__ H,
                                                  const int* __restrict__ rowptr,
                                                  const int* __restrict__ col,
                                                  const float* __restrict__ dinv,
                                                  const float* __restrict__ bias,
                                                  float* __restrict__ Xo) {
    int n = blockIdx.x;
    int c = threadIdx.x;
    int lo = rowptr[n];
    int hi = rowptr[n + 1];
    float dn = dinv[n];
    float acc = bias[c] + 2.0f * dn * dn * H[(size_t)n * F + c];
    for (int i = lo; i < hi; i++) {
        int s = col[i];
        float w = dinv[s] * dn;
        acc = fmaf(w, H[(size_t)s * F + c], acc);
    }
    Xo[(size_t)n * F + c] = fmaxf(acc, 0.f);
}

// ---------------- Fused mean-pool + FC1(relu) + FC2 ----------------
// batch[] is sorted; block g binary-searches its node range.

__global__ __launch_bounds__(128) void pool_fc_kernel(const float* __restrict__ x,
                                                      const int* __restrict__ batch,
                                                      const float* __restrict__ fc1w,
                                                      const float* __restrict__ fc1b,
                                                      const float* __restrict__ fc2w,
                                                      const float* __restrict__ fc2b,
                                                      float* __restrict__ out) {
    __shared__ float pooled[F];
    __shared__ int bnd[2];
    __shared__ float red[2];
    int g = blockIdx.x, t = threadIdx.x;
    if (t < 2) {
        int target = g + t;
        int lo = 0, hi = N_NODES;
        while (lo < hi) {
            int m = (lo + hi) >> 1;
            if (batch[m] < target) lo = m + 1;
            else hi = m;
        }
        bnd[t] = lo;
    }
    __syncthreads();
    int lo = bnd[0], hi = bnd[1];
    float s = 0.f;
    for (int n = lo; n < hi; n++) s += x[(size_t)n * F + t];
    float c = fmaxf((float)(hi - lo), 1.0f);
    pooled[t] = s / c;
    __syncthreads();

    float acc = fc1b[t];
#pragma unroll 4
    for (int k = 0; k < F; k++) acc = fmaf(pooled[k], fc1w[k * F + t], acc);
    acc = fmaxf(acc, 0.f);

    float p = acc * fc2w[t];
#pragma unroll
    for (int o = 32; o > 0; o >>= 1) p += __shfl_down(p, o, 64);
    if ((t & 63) == 0) red[t >> 6] = p;
    __syncthreads();
    if (t == 0) out[g] = red[0] + red[1] + fc2b[0];
}

// ---------------- launch ----------------

extern "C" void kernel_launch(void* const* d_in, const int* in_sizes, int n_in,
                              void* d_out, int out_size, void* d_ws, size_t ws_size,
                              hipStream_t stream) {
    const float* x_in   = (const float*)d_in[0];
    const int*   eidx   = (const int*)d_in[1];
    const int*   batch  = (const int*)d_in[2];
    // d_in[3] = batch_size scalar (==N_GRAPHS), unused
    const float* conv_w = (const float*)d_in[4];
    const float* conv_b = (const float*)d_in[5];
    const float* fc1w   = (const float*)d_in[6];
    const float* fc1b   = (const float*)d_in[7];
    const float* fc2w   = (const float*)d_in[8];
    const float* fc2b   = (const float*)d_in[9];
    float* out = (float*)d_out;

    const int* src = eidx;            // edge_index[0]
    const int* dst = eidx + N_EDGES;  // edge_index[1]

    char* ws = (char*)d_ws;
    size_t off = 0;
    auto alloc = [&](size_t bytes) -> char* {
        char* p = ws + off;
        off += (bytes + 255) & ~(size_t)255;
        return p;
    };
    float* bufA  = (float*)alloc((size_t)N_NODES * F * 4);   // 51.2 MB
    float* bufB  = (float*)alloc((size_t)N_NODES * F * 4);   // 51.2 MB
    float* dinv  = (float*)alloc((size_t)N_NODES * 4);
    int*   cnt   = (int*)alloc((size_t)N_NODES * 4);
    int*   rowp  = (int*)alloc((size_t)(N_NODES + 1) * 4);
    int*   fill  = (int*)alloc((size_t)N_NODES * 4);
    int*   col   = (int*)alloc((size_t)N_EDGES * 4);         // 6.4 MB
    int*   blks  = (int*)alloc(128 * 4);
    (void)ws_size; (void)in_sizes; (void)n_in; (void)out_size;

    // --- CSR build (once; reused by all 4 layers) ---
    hipMemsetAsync(cnt, 0, (size_t)N_NODES * 4, stream);
    count_kernel<<<(N_EDGES + 255) / 256, 256, 0, stream>>>(dst, cnt);
    dinv_kernel<<<(N_NODES + 255) / 256, 256, 0, stream>>>(cnt, dinv);
    scan1_kernel<<<SCAN_NBLK, 256, 0, stream>>>(cnt, rowp, blks);
    scan2_kernel<<<1, 128, 0, stream>>>(blks, SCAN_NBLK);
    scan3_kernel<<<SCAN_NBLK, 256, 0, stream>>>(rowp, blks, fill);
    fill_kernel<<<(N_EDGES + 255) / 256, 256, 0, stream>>>(src, dst, fill, col);

    // --- 4 GCN layers: GEMM (cur -> bufB), gather-agg+relu (bufB -> bufA) ---
    const float* cur = x_in;
    for (int L = 0; L < N_CONVS; L++) {
        gemm_kernel<<<(N_NODES + 63) / 64, 256, 0, stream>>>(
            cur, conv_w + (size_t)L * F * F, bufB);
        agg_kernel<<<N_NODES, 128, 0, stream>>>(
            bufB, rowp, col, dinv, conv_b + (size_t)L * F, bufA);
        cur = bufA;
    }

    // --- mean-pool + FC head ---
    pool_fc_kernel<<<N_GRAPHS, 128, 0, stream>>>(bufA, batch, fc1w, fc1b, fc2w, fc2b, out);
}

// Round 2
// 970.084 us; speedup vs baseline: 1.2942x; 1.2942x over previous
//
#include <hip/hip_runtime.h>

#define N_NODES 100000
#define N_EDGES 1600000
#define N_GRAPHS 512
#define F 128
#define N_CONVS 4
#define SCAN_NBLK ((N_NODES + 1023) / 1024)   // 98

__device__ __forceinline__ float4 fma4(float w, float4 v, float4 a) {
    a.x = fmaf(w, v.x, a.x); a.y = fmaf(w, v.y, a.y);
    a.z = fmaf(w, v.z, a.z); a.w = fmaf(w, v.w, a.w);
    return a;
}

// ---------------- CSR build ----------------

__global__ void count_kernel(const int* __restrict__ dst, int* __restrict__ cnt) {
    int e = blockIdx.x * blockDim.x + threadIdx.x;
    if (e < N_EDGES) atomicAdd(&cnt[dst[e]], 1);
}

__global__ void dinv_kernel(const int* __restrict__ cnt, float* __restrict__ dinv) {
    int n = blockIdx.x * blockDim.x + threadIdx.x;
    if (n < N_NODES) dinv[n] = rsqrtf((float)cnt[n] + 2.0f);  // improved=True: +2 self loop
}

// Exclusive scan of cnt[] into rowptr[], hierarchical (1024 elems/block).
__global__ void scan1_kernel(const int* __restrict__ cnt, int* __restrict__ excl,
                             int* __restrict__ blksum) {
    __shared__ int sums[256];
    int t = threadIdx.x;
    int base = blockIdx.x * 1024 + t * 4;
    int v0 = 0, v1 = 0, v2 = 0, v3 = 0;
    if (base + 0 < N_NODES) v0 = cnt[base + 0];
    if (base + 1 < N_NODES) v1 = cnt[base + 1];
    if (base + 2 < N_NODES) v2 = cnt[base + 2];
    if (base + 3 < N_NODES) v3 = cnt[base + 3];
    int s = v0 + v1 + v2 + v3;
    sums[t] = s;
    __syncthreads();
    for (int off = 1; off < 256; off <<= 1) {
        int y = (t >= off) ? sums[t - off] : 0;
        __syncthreads();
        sums[t] += y;
        __syncthreads();
    }
    int pre = sums[t] - s;
    if (base + 0 < N_NODES) excl[base + 0] = pre;
    if (base + 1 < N_NODES) excl[base + 1] = pre + v0;
    if (base + 2 < N_NODES) excl[base + 2] = pre + v0 + v1;
    if (base + 3 < N_NODES) excl[base + 3] = pre + v0 + v1 + v2;
    if (t == 255) blksum[blockIdx.x] = sums[255];
}

__global__ void scan2_kernel(int* __restrict__ blksum, int nblk) {
    __shared__ int sh[128];
    int t = threadIdx.x;
    int v = (t < nblk) ? blksum[t] : 0;
    sh[t] = v;
    __syncthreads();
    for (int off = 1; off < 128; off <<= 1) {
        int y = (t >= off) ? sh[t - off] : 0;
        __syncthreads();
        sh[t] += y;
        __syncthreads();
    }
    if (t < nblk) blksum[t] = sh[t] - v;
}

__global__ void scan3_kernel(int* __restrict__ rowptr, const int* __restrict__ blksum,
                             int* __restrict__ fill) {
    int t = threadIdx.x;
    int base = blockIdx.x * 1024 + t * 4;
    int off = blksum[blockIdx.x];
#pragma unroll
    for (int i = 0; i < 4; i++) {
        int idx = base + i;
        if (idx < N_NODES) {
            int v = rowptr[idx] + off;
            rowptr[idx] = v;
            fill[idx] = v;
        }
    }
    if (blockIdx.x == 0 && t == 0) rowptr[N_NODES] = N_EDGES;
}

// Fill CSR col[] and per-edge weight ew[] = dinv[src]*dinv[dst] (CSR order).
__global__ void fill_kernel(const int* __restrict__ src, const int* __restrict__ dst,
                            const float* __restrict__ dinv,
                            int* __restrict__ fill, int* __restrict__ col,
                            float* __restrict__ ew) {
    int e = blockIdx.x * blockDim.x + threadIdx.x;
    if (e < N_EDGES) {
        int d = dst[e];
        int s = src[e];
        int pos = atomicAdd(&fill[d], 1);
        col[pos] = s;
        ew[pos] = dinv[s] * dinv[d];
    }
}

// ---------------- GEMM: H = X @ W   (M=100000, K=N=128, fp32) ----------------

__global__ __launch_bounds__(256) void gemm_kernel(const float* __restrict__ X,
                                                   const float* __restrict__ W,
                                                   float* __restrict__ H) {
    __shared__ float xs[64 * 132];
    int t = threadIdx.x;
    int row0 = blockIdx.x * 64;

#pragma unroll
    for (int i = 0; i < 8; i++) {
        int idx = i * 256 + t;
        int r = idx >> 5;
        int c4 = idx & 31;
        float4 v = make_float4(0.f, 0.f, 0.f, 0.f);
        int row = row0 + r;
        if (row < N_NODES) v = *(const float4*)(X + (size_t)row * F + c4 * 4);
        *(float4*)(&xs[r * 132 + c4 * 4]) = v;
    }
    __syncthreads();

    int cg = t & 31;
    int rg = t >> 5;
    const float4* W4 = (const float4*)W;

    float acc[8][4];
#pragma unroll
    for (int i = 0; i < 8; i++)
#pragma unroll
        for (int j = 0; j < 4; j++) acc[i][j] = 0.f;

#pragma unroll 4
    for (int k = 0; k < F; k++) {
        float4 w = W4[k * 32 + cg];
#pragma unroll
        for (int i = 0; i < 8; i++) {
            float xv = xs[(rg * 8 + i) * 132 + k];
            acc[i][0] = fmaf(xv, w.x, acc[i][0]);
            acc[i][1] = fmaf(xv, w.y, acc[i][1]);
            acc[i][2] = fmaf(xv, w.z, acc[i][2]);
            acc[i][3] = fmaf(xv, w.w, acc[i][3]);
        }
    }

#pragma unroll
    for (int i = 0; i < 8; i++) {
        int row = row0 + rg * 8 + i;
        if (row < N_NODES) {
            float4 o = make_float4(acc[i][0], acc[i][1], acc[i][2], acc[i][3]);
            *(float4*)(H + (size_t)row * F + cg * 4) = o;
        }
    }
}

// ---------------- Aggregation: x_out = relu(agg + 2*dinv^2*h + b) ----------------
// One WAVE per node. Lane = 64: cg = lane&31 (float4 channel group),
// h = lane>>5 (edge parity). 4x unrolled per half -> 8 H-row gathers in flight
// per wave. Block = 256 threads = 4 nodes.

__global__ __launch_bounds__(256) void agg_kernel(const float4* __restrict__ H4,
                                                  const int* __restrict__ rowptr,
                                                  const int* __restrict__ col,
                                                  const float* __restrict__ ew,
                                                  const float* __restrict__ dinv,
                                                  const float4* __restrict__ bias4,
                                                  float4* __restrict__ Xo4) {
    int node = blockIdx.x * 4 + (threadIdx.x >> 6);
    if (node >= N_NODES) return;
    int lane = threadIdx.x & 63;
    int cg = lane & 31;
    int h = lane >> 5;

    int lo = rowptr[node];
    int hi = rowptr[node + 1];

    float4 a0 = make_float4(0.f, 0.f, 0.f, 0.f);
    float4 a1 = a0, a2 = a0, a3 = a0;

    int i = lo + h;
    for (; i + 6 < hi; i += 8) {
        int s0 = col[i];
        int s1 = col[i + 2];
        int s2 = col[i + 4];
        int s3 = col[i + 6];
        float w0 = ew[i];
        float w1 = ew[i + 2];
        float w2 = ew[i + 4];
        float w3 = ew[i + 6];
        float4 v0 = H4[(size_t)s0 * 32 + cg];
        float4 v1 = H4[(size_t)s1 * 32 + cg];
        float4 v2 = H4[(size_t)s2 * 32 + cg];
        float4 v3 = H4[(size_t)s3 * 32 + cg];
        a0 = fma4(w0, v0, a0);
        a1 = fma4(w1, v1, a1);
        a2 = fma4(w2, v2, a2);
        a3 = fma4(w3, v3, a3);
    }
    for (; i < hi; i += 2) {
        int s = col[i];
        float w = ew[i];
        a0 = fma4(w, H4[(size_t)s * 32 + cg], a0);
    }

    a0.x += a1.x + a2.x + a3.x;
    a0.y += a1.y + a2.y + a3.y;
    a0.z += a1.z + a2.z + a3.z;
    a0.w += a1.w + a2.w + a3.w;

    // combine odd-edge half into even-edge half (lanes 0-31 <- lanes 32-63)
    a0.x += __shfl_down(a0.x, 32, 64);
    a0.y += __shfl_down(a0.y, 32, 64);
    a0.z += __shfl_down(a0.z, 32, 64);
    a0.w += __shfl_down(a0.w, 32, 64);

    if (h == 0) {
        float dn = dinv[node];
        float sw = 2.0f * dn * dn;
        float4 hv = H4[(size_t)node * 32 + cg];
        float4 bv = bias4[cg];
        float4 r;
        r.x = fmaxf(fmaf(sw, hv.x, a0.x) + bv.x, 0.f);
        r.y = fmaxf(fmaf(sw, hv.y, a0.y) + bv.y, 0.f);
        r.z = fmaxf(fmaf(sw, hv.z, a0.z) + bv.z, 0.f);
        r.w = fmaxf(fmaf(sw, hv.w, a0.w) + bv.w, 0.f);
        Xo4[(size_t)node * 32 + cg] = r;
    }
}

// ---------------- Fused mean-pool + FC1(relu) + FC2 ----------------
// 256 threads: channel c = t&127, half = t>>7 splits the node range (2-way) +
// 4x unroll for MLP in the streaming reduction.

__global__ __launch_bounds__(256) void pool_fc_kernel(const float* __restrict__ x,
                                                      const int* __restrict__ batch,
                                                      const float* __restrict__ fc1w,
                                                      const float* __restrict__ fc1b,
                                                      const float* __restrict__ fc2w,
                                                      const float* __restrict__ fc2b,
                                                      float* __restrict__ out) {
    __shared__ float part[2][F];
    __shared__ float pooled[F];
    __shared__ int bnd[2];
    __shared__ float red[2];
    int g = blockIdx.x, t = threadIdx.x;
    int c = t & 127, hlf = t >> 7;

    if (t < 2) {
        int target = g + t;
        int lo = 0, hi = N_NODES;
        while (lo < hi) {
            int m = (lo + hi) >> 1;
            if (batch[m] < target) lo = m + 1;
            else hi = m;
        }
        bnd[t] = lo;
    }
    __syncthreads();
    int lo = bnd[0], hi = bnd[1];

    float s = 0.f;
    int n = lo + hlf;
    for (; n + 6 < hi; n += 8) {
        float v0 = x[(size_t)n * F + c];
        float v1 = x[(size_t)(n + 2) * F + c];
        float v2 = x[(size_t)(n + 4) * F + c];
        float v3 = x[(size_t)(n + 6) * F + c];
        s += (v0 + v1) + (v2 + v3);
    }
    for (; n < hi; n += 2) s += x[(size_t)n * F + c];
    part[hlf][c] = s;
    __syncthreads();

    if (t < F) {
        float cntf = fmaxf((float)(hi - lo), 1.0f);
        pooled[c] = (part[0][c] + part[1][c]) / cntf;
    }
    __syncthreads();

    if (t < F) {
        float acc = fc1b[t];
#pragma unroll 4
        for (int k = 0; k < F; k++) acc = fmaf(pooled[k], fc1w[k * F + t], acc);
        acc = fmaxf(acc, 0.f);

        float p = acc * fc2w[t];
#pragma unroll
        for (int o = 32; o > 0; o >>= 1) p += __shfl_down(p, o, 64);
        if ((t & 63) == 0) red[t >> 6] = p;
    }
    __syncthreads();
    if (t == 0) out[g] = red[0] + red[1] + fc2b[0];
}

// ---------------- launch ----------------

extern "C" void kernel_launch(void* const* d_in, const int* in_sizes, int n_in,
                              void* d_out, int out_size, void* d_ws, size_t ws_size,
                              hipStream_t stream) {
    const float* x_in   = (const float*)d_in[0];
    const int*   eidx   = (const int*)d_in[1];
    const int*   batch  = (const int*)d_in[2];
    const float* conv_w = (const float*)d_in[4];
    const float* conv_b = (const float*)d_in[5];
    const float* fc1w   = (const float*)d_in[6];
    const float* fc1b   = (const float*)d_in[7];
    const float* fc2w   = (const float*)d_in[8];
    const float* fc2b   = (const float*)d_in[9];
    float* out = (float*)d_out;

    const int* src = eidx;
    const int* dst = eidx + N_EDGES;

    char* ws = (char*)d_ws;
    size_t off = 0;
    auto alloc = [&](size_t bytes) -> char* {
        char* p = ws + off;
        off += (bytes + 255) & ~(size_t)255;
        return p;
    };
    float* bufA  = (float*)alloc((size_t)N_NODES * F * 4);   // 51.2 MB
    float* bufB  = (float*)alloc((size_t)N_NODES * F * 4);   // 51.2 MB
    float* dinv  = (float*)alloc((size_t)N_NODES * 4);
    int*   cnt   = (int*)alloc((size_t)N_NODES * 4);
    int*   rowp  = (int*)alloc((size_t)(N_NODES + 1) * 4);
    int*   fill  = (int*)alloc((size_t)N_NODES * 4);
    int*   col   = (int*)alloc((size_t)N_EDGES * 4);         // 6.4 MB
    float* ew    = (float*)alloc((size_t)N_EDGES * 4);       // 6.4 MB
    int*   blks  = (int*)alloc(128 * 4);
    (void)ws_size; (void)in_sizes; (void)n_in; (void)out_size;

    // --- CSR build (once; reused by all 4 layers) ---
    hipMemsetAsync(cnt, 0, (size_t)N_NODES * 4, stream);
    count_kernel<<<(N_EDGES + 255) / 256, 256, 0, stream>>>(dst, cnt);
    dinv_kernel<<<(N_NODES + 255) / 256, 256, 0, stream>>>(cnt, dinv);
    scan1_kernel<<<SCAN_NBLK, 256, 0, stream>>>(cnt, rowp, blks);
    scan2_kernel<<<1, 128, 0, stream>>>(blks, SCAN_NBLK);
    scan3_kernel<<<SCAN_NBLK, 256, 0, stream>>>(rowp, blks, fill);
    fill_kernel<<<(N_EDGES + 255) / 256, 256, 0, stream>>>(src, dst, dinv, fill, col, ew);

    // --- 4 GCN layers ---
    const float* cur = x_in;
    for (int L = 0; L < N_CONVS; L++) {
        gemm_kernel<<<(N_NODES + 63) / 64, 256, 0, stream>>>(
            cur, conv_w + (size_t)L * F * F, bufB);
        agg_kernel<<<(N_NODES + 3) / 4, 256, 0, stream>>>(
            (const float4*)bufB, rowp, col, ew, dinv,
            (const float4*)(conv_b + (size_t)L * F), (float4*)bufA);
        cur = bufA;
    }

    // --- mean-pool + FC head ---
    pool_fc_kernel<<<N_GRAPHS, 256, 0, stream>>>(bufA, batch, fc1w, fc1b, fc2w, fc2b, out);
}

// Round 3
// 948.057 us; speedup vs baseline: 1.3243x; 1.0232x over previous
//
#include <hip/hip_runtime.h>

#define N_NODES 100000
#define N_EDGES 1600000
#define N_GRAPHS 512
#define F 128
#define N_CONVS 4
#define SCAN_NBLK ((N_NODES + 1023) / 1024)   // 98

__device__ __forceinline__ float4 fma4(float w, float4 v, float4 a) {
    a.x = fmaf(w, v.x, a.x); a.y = fmaf(w, v.y, a.y);
    a.z = fmaf(w, v.z, a.z); a.w = fmaf(w, v.w, a.w);
    return a;
}

// ---------------- CSR build ----------------

__global__ void count_kernel(const int* __restrict__ dst, int* __restrict__ cnt) {
    int e = blockIdx.x * blockDim.x + threadIdx.x;
    if (e < N_EDGES) atomicAdd(&cnt[dst[e]], 1);
}

__global__ void dinv_kernel(const int* __restrict__ cnt, float* __restrict__ dinv) {
    int n = blockIdx.x * blockDim.x + threadIdx.x;
    if (n < N_NODES) dinv[n] = rsqrtf((float)cnt[n] + 2.0f);  // improved=True: +2 self loop
}

__global__ void scan1_kernel(const int* __restrict__ cnt, int* __restrict__ excl,
                             int* __restrict__ blksum) {
    __shared__ int sums[256];
    int t = threadIdx.x;
    int base = blockIdx.x * 1024 + t * 4;
    int v0 = 0, v1 = 0, v2 = 0, v3 = 0;
    if (base + 0 < N_NODES) v0 = cnt[base + 0];
    if (base + 1 < N_NODES) v1 = cnt[base + 1];
    if (base + 2 < N_NODES) v2 = cnt[base + 2];
    if (base + 3 < N_NODES) v3 = cnt[base + 3];
    int s = v0 + v1 + v2 + v3;
    sums[t] = s;
    __syncthreads();
    for (int off = 1; off < 256; off <<= 1) {
        int y = (t >= off) ? sums[t - off] : 0;
        __syncthreads();
        sums[t] += y;
        __syncthreads();
    }
    int pre = sums[t] - s;
    if (base + 0 < N_NODES) excl[base + 0] = pre;
    if (base + 1 < N_NODES) excl[base + 1] = pre + v0;
    if (base + 2 < N_NODES) excl[base + 2] = pre + v0 + v1;
    if (base + 3 < N_NODES) excl[base + 3] = pre + v0 + v1 + v2;
    if (t == 255) blksum[blockIdx.x] = sums[255];
}

__global__ void scan2_kernel(int* __restrict__ blksum, int nblk) {
    __shared__ int sh[128];
    int t = threadIdx.x;
    int v = (t < nblk) ? blksum[t] : 0;
    sh[t] = v;
    __syncthreads();
    for (int off = 1; off < 128; off <<= 1) {
        int y = (t >= off) ? sh[t - off] : 0;
        __syncthreads();
        sh[t] += y;
        __syncthreads();
    }
    if (t < nblk) blksum[t] = sh[t] - v;
}

__global__ void scan3_kernel(int* __restrict__ rowptr, const int* __restrict__ blksum,
                             int* __restrict__ fill) {
    int t = threadIdx.x;
    int base = blockIdx.x * 1024 + t * 4;
    int off = blksum[blockIdx.x];
#pragma unroll
    for (int i = 0; i < 4; i++) {
        int idx = base + i;
        if (idx < N_NODES) {
            int v = rowptr[idx] + off;
            rowptr[idx] = v;
            fill[idx] = v;
        }
    }
    if (blockIdx.x == 0 && t == 0) rowptr[N_NODES] = N_EDGES;
}

__global__ void fill_kernel(const int* __restrict__ src, const int* __restrict__ dst,
                            const float* __restrict__ dinv,
                            int* __restrict__ fill, int* __restrict__ col,
                            float* __restrict__ ew) {
    int e = blockIdx.x * blockDim.x + threadIdx.x;
    if (e < N_EDGES) {
        int d = dst[e];
        int s = src[e];
        int pos = atomicAdd(&fill[d], 1);
        col[pos] = s;
        ew[pos] = dinv[s] * dinv[d];
    }
}

// ---------------- GEMM: H = X @ W   (M=100000, K=N=128, fp32) ----------------
// 256 threads, 64 rows/block, thread = 8 rows x 4 cols. Inner loop vectorized
// over k: ds_read_b128 of xs (broadcast across half-wave), 4 W float4 rows,
// 128 FMAs per k4 step -> VALU-bound.

__global__ __launch_bounds__(256) void gemm_kernel(const float* __restrict__ X,
                                                   const float* __restrict__ W,
                                                   float* __restrict__ H) {
    __shared__ float xs[64 * 132];   // 132-stride: 528 B rows, 16 B aligned
    int t = threadIdx.x;
    int row0 = blockIdx.x * 64;

#pragma unroll
    for (int i = 0; i < 8; i++) {
        int idx = i * 256 + t;
        int r = idx >> 5;
        int c4 = idx & 31;
        float4 v = make_float4(0.f, 0.f, 0.f, 0.f);
        int row = row0 + r;
        if (row < N_NODES) v = *(const float4*)(X + (size_t)row * F + c4 * 4);
        *(float4*)(&xs[r * 132 + c4 * 4]) = v;
    }
    __syncthreads();

    int cg = t & 31;   // output col group (4 cols)
    int rg = t >> 5;   // row group (8 rows)
    const float4* W4 = (const float4*)W;

    float4 acc[8];
#pragma unroll
    for (int i = 0; i < 8; i++) acc[i] = make_float4(0.f, 0.f, 0.f, 0.f);

#pragma unroll 2
    for (int k4 = 0; k4 < 32; k4++) {
        float4 xv[8];
#pragma unroll
        for (int i = 0; i < 8; i++)
            xv[i] = *(const float4*)(&xs[(rg * 8 + i) * 132 + k4 * 4]);
        float4 w0 = W4[(k4 * 4 + 0) * 32 + cg];
        float4 w1 = W4[(k4 * 4 + 1) * 32 + cg];
        float4 w2 = W4[(k4 * 4 + 2) * 32 + cg];
        float4 w3 = W4[(k4 * 4 + 3) * 32 + cg];
#pragma unroll
        for (int i = 0; i < 8; i++) {
            acc[i] = fma4(xv[i].x, w0, acc[i]);
            acc[i] = fma4(xv[i].y, w1, acc[i]);
            acc[i] = fma4(xv[i].z, w2, acc[i]);
            acc[i] = fma4(xv[i].w, w3, acc[i]);
        }
    }

#pragma unroll
    for (int i = 0; i < 8; i++) {
        int row = row0 + rg * 8 + i;
        if (row < N_NODES)
            *(float4*)(H + (size_t)row * F + cg * 4) = acc[i];
    }
}

// ---------------- Aggregation: x_out = relu(agg + 2*dinv^2*h + b) ----------------
// One wave per node; lane halves process even/odd edges; 8 predicated slots
// per half per iteration (16 edges/wave/iter) -> up to 16 H-row gathers in
// flight, no serial tail (indices clamped, weights zeroed past hi).

__global__ __launch_bounds__(256) void agg_kernel(const float4* __restrict__ H4,
                                                  const int* __restrict__ rowptr,
                                                  const int* __restrict__ col,
                                                  const float* __restrict__ ew,
                                                  const float* __restrict__ dinv,
                                                  const float4* __restrict__ bias4,
                                                  float4* __restrict__ Xo4) {
    int node = blockIdx.x * 4 + (threadIdx.x >> 6);
    if (node >= N_NODES) return;
    int lane = threadIdx.x & 63;
    int cg = lane & 31;
    int h = lane >> 5;

    int lo = rowptr[node];
    int hi = rowptr[node + 1];
    int him1 = hi - 1;

    float4 a[4];
#pragma unroll
    for (int j = 0; j < 4; j++) a[j] = make_float4(0.f, 0.f, 0.f, 0.f);

    for (int i = lo + h; i < hi; i += 16) {
        int s[8]; float w[8]; float4 v[8];
#pragma unroll
        for (int j = 0; j < 8; j++) {
            int ij = i + 2 * j;
            int cj = (ij < him1) ? ij : him1;   // clamp: load always valid
            s[j] = col[cj];
            float wj = ew[cj];
            w[j] = (ij < hi) ? wj : 0.f;        // zero weight past end
        }
#pragma unroll
        for (int j = 0; j < 8; j++) v[j] = H4[(size_t)s[j] * 32 + cg];
#pragma unroll
        for (int j = 0; j < 8; j++) a[j & 3] = fma4(w[j], v[j], a[j & 3]);
    }

    float4 a0;
    a0.x = (a[0].x + a[1].x) + (a[2].x + a[3].x);
    a0.y = (a[0].y + a[1].y) + (a[2].y + a[3].y);
    a0.z = (a[0].z + a[1].z) + (a[2].z + a[3].z);
    a0.w = (a[0].w + a[1].w) + (a[2].w + a[3].w);

    a0.x += __shfl_down(a0.x, 32, 64);
    a0.y += __shfl_down(a0.y, 32, 64);
    a0.z += __shfl_down(a0.z, 32, 64);
    a0.w += __shfl_down(a0.w, 32, 64);

    if (h == 0) {
        float dn = dinv[node];
        float sw = 2.0f * dn * dn;
        float4 hv = H4[(size_t)node * 32 + cg];
        float4 bv = bias4[cg];
        float4 r;
        r.x = fmaxf(fmaf(sw, hv.x, a0.x) + bv.x, 0.f);
        r.y = fmaxf(fmaf(sw, hv.y, a0.y) + bv.y, 0.f);
        r.z = fmaxf(fmaf(sw, hv.z, a0.z) + bv.z, 0.f);
        r.w = fmaxf(fmaf(sw, hv.w, a0.w) + bv.w, 0.f);
        Xo4[(size_t)node * 32 + cg] = r;
    }
}

// ---------------- Fused mean-pool + FC1(relu) + FC2 ----------------

__global__ __launch_bounds__(256) void pool_fc_kernel(const float* __restrict__ x,
                                                      const int* __restrict__ batch,
                                                      const float* __restrict__ fc1w,
                                                      const float* __restrict__ fc1b,
                                                      const float* __restrict__ fc2w,
                                                      const float* __restrict__ fc2b,
                                                      float* __restrict__ out) {
    __shared__ float part[2][F];
    __shared__ float pooled[F];
    __shared__ int bnd[2];
    __shared__ float red[2];
    int g = blockIdx.x, t = threadIdx.x;
    int c = t & 127, hlf = t >> 7;

    if (t < 2) {
        int target = g + t;
        int lo = 0, hi = N_NODES;
        while (lo < hi) {
            int m = (lo + hi) >> 1;
            if (batch[m] < target) lo = m + 1;
            else hi = m;
        }
        bnd[t] = lo;
    }
    __syncthreads();
    int lo = bnd[0], hi = bnd[1];

    float s = 0.f;
    int n = lo + hlf;
    for (; n + 6 < hi; n += 8) {
        float v0 = x[(size_t)n * F + c];
        float v1 = x[(size_t)(n + 2) * F + c];
        float v2 = x[(size_t)(n + 4) * F + c];
        float v3 = x[(size_t)(n + 6) * F + c];
        s += (v0 + v1) + (v2 + v3);
    }
    for (; n < hi; n += 2) s += x[(size_t)n * F + c];
    part[hlf][c] = s;
    __syncthreads();

    if (t < F) {
        float cntf = fmaxf((float)(hi - lo), 1.0f);
        pooled[c] = (part[0][c] + part[1][c]) / cntf;
    }
    __syncthreads();

    if (t < F) {
        float acc = fc1b[t];
#pragma unroll 4
        for (int k = 0; k < F; k++) acc = fmaf(pooled[k], fc1w[k * F + t], acc);
        acc = fmaxf(acc, 0.f);

        float p = acc * fc2w[t];
#pragma unroll
        for (int o = 32; o > 0; o >>= 1) p += __shfl_down(p, o, 64);
        if ((t & 63) == 0) red[t >> 6] = p;
    }
    __syncthreads();
    if (t == 0) out[g] = red[0] + red[1] + fc2b[0];
}

// ---------------- launch ----------------

extern "C" void kernel_launch(void* const* d_in, const int* in_sizes, int n_in,
                              void* d_out, int out_size, void* d_ws, size_t ws_size,
                              hipStream_t stream) {
    const float* x_in   = (const float*)d_in[0];
    const int*   eidx   = (const int*)d_in[1];
    const int*   batch  = (const int*)d_in[2];
    const float* conv_w = (const float*)d_in[4];
    const float* conv_b = (const float*)d_in[5];
    const float* fc1w   = (const float*)d_in[6];
    const float* fc1b   = (const float*)d_in[7];
    const float* fc2w   = (const float*)d_in[8];
    const float* fc2b   = (const float*)d_in[9];
    float* out = (float*)d_out;

    const int* src = eidx;
    const int* dst = eidx + N_EDGES;

    char* ws = (char*)d_ws;
    size_t off = 0;
    auto alloc = [&](size_t bytes) -> char* {
        char* p = ws + off;
        off += (bytes + 255) & ~(size_t)255;
        return p;
    };
    float* bufA  = (float*)alloc((size_t)N_NODES * F * 4);   // 51.2 MB
    float* bufB  = (float*)alloc((size_t)N_NODES * F * 4);   // 51.2 MB
    float* dinv  = (float*)alloc((size_t)N_NODES * 4);
    int*   cnt   = (int*)alloc((size_t)N_NODES * 4);
    int*   rowp  = (int*)alloc((size_t)(N_NODES + 1) * 4);
    int*   fill  = (int*)alloc((size_t)N_NODES * 4);
    int*   col   = (int*)alloc((size_t)N_EDGES * 4);         // 6.4 MB
    float* ew    = (float*)alloc((size_t)N_EDGES * 4);       // 6.4 MB
    int*   blks  = (int*)alloc(128 * 4);
    (void)ws_size; (void)in_sizes; (void)n_in; (void)out_size;

    // --- CSR build (once; reused by all 4 layers) ---
    hipMemsetAsync(cnt, 0, (size_t)N_NODES * 4, stream);
    count_kernel<<<(N_EDGES + 255) / 256, 256, 0, stream>>>(dst, cnt);
    dinv_kernel<<<(N_NODES + 255) / 256, 256, 0, stream>>>(cnt, dinv);
    scan1_kernel<<<SCAN_NBLK, 256, 0, stream>>>(cnt, rowp, blks);
    scan2_kernel<<<1, 128, 0, stream>>>(blks, SCAN_NBLK);
    scan3_kernel<<<SCAN_NBLK, 256, 0, stream>>>(rowp, blks, fill);
    fill_kernel<<<(N_EDGES + 255) / 256, 256, 0, stream>>>(src, dst, dinv, fill, col, ew);

    // --- 4 GCN layers ---
    const float* cur = x_in;
    for (int L = 0; L < N_CONVS; L++) {
        gemm_kernel<<<(N_NODES + 63) / 64, 256, 0, stream>>>(
            cur, conv_w + (size_t)L * F * F, bufB);
        agg_kernel<<<(N_NODES + 3) / 4, 256, 0, stream>>>(
            (const float4*)bufB, rowp, col, ew, dinv,
            (const float4*)(conv_b + (size_t)L * F), (float4*)bufA);
        cur = bufA;
    }

    // --- mean-pool + FC head ---
    pool_fc_kernel<<<N_GRAPHS, 256, 0, stream>>>(bufA, batch, fc1w, fc1b, fc2w, fc2b, out);
}